// Round 1
// baseline (8876.513 us; speedup 1.0000x reference)
//
#include <hip/hip_runtime.h>
#include <hip/hip_bf16.h>

// Problem constants
#define TT 512
#define BB 256
#define II 120
#define HH 128
#define GG 512   // 4*H
#define D1 512
#define NOUT 7
#define TB (TT*BB)  // 131072

// ---------- static device scratch (avoids ws_size dependence) ----------
__device__ unsigned short g_xg[TB * GG];   // [T*B, 512] bf16  (128 MB)
__device__ unsigned short g_h0[TB * HH];   // [T*B, 128] bf16  (32 MB)
__device__ float          g_pooled[BB * HH];

// ---------- helpers ----------
__device__ inline float bf2f(unsigned short u) {
    return __uint_as_float(((unsigned)u) << 16);
}
__device__ inline unsigned short f2bf(float f) {
    unsigned u = __float_as_uint(f);
    return (unsigned short)((u + 0x7fffu + ((u >> 16) & 1u)) >> 16);
}
__device__ inline float sigm(float x) {
    return 1.0f / (1.0f + __expf(-x));
}
__device__ inline float tanh_fast(float x) {
    x = fminf(fmaxf(x, -15.f), 15.f);
    float e = __expf(2.f * x);
    return (e - 1.f) / (e + 1.f);
}

// ---------- GEMM: xg[n,g] = sum_k A[n,k] * W[g,k] + bia[g] + bib[g] ----------
// block: 16 rows x 256 cols, 256 threads, thread computes 4x4 micro-tile
// LAYER 0: A = input_seq (f32, F=120); LAYER 1: A = g_h0 (bf16, F=128)
template <int LAYER>
__global__ __launch_bounds__(256) void gemm_xg_kernel(
    const float* __restrict__ A0,
    const float* __restrict__ W,      // [512, F]
    const float* __restrict__ bia,
    const float* __restrict__ bib)
{
    const int F  = (LAYER == 0) ? II : HH;
    const int n0 = blockIdx.x * 16;
    const int c0 = blockIdx.y * 256;
    const int t  = threadIdx.x;
    const int rg = t >> 6;    // 0..3  (4 rows each)
    const int cg = t & 63;    // 0..63 (4 cols each)

    __shared__ __align__(16) float xs[32][20];    // [kk][row]
    __shared__ __align__(16) float wsh[32][260];  // [kk][col]

    float acc[4][4];
#pragma unroll
    for (int r = 0; r < 4; ++r)
#pragma unroll
        for (int c = 0; c < 4; ++c) acc[r][c] = 0.f;

    for (int k0 = 0; k0 < F; k0 += 32) {
        // stage A tile (32k x 16 rows)
#pragma unroll
        for (int i = 0; i < 2; ++i) {
            int idx = t + i * 256;
            int kk = idx & 31, row = idx >> 5;
            int k = k0 + kk;
            float v = 0.f;
            if (k < F) {
                if (LAYER == 0) v = A0[(size_t)(n0 + row) * II + k];
                else            v = bf2f(g_h0[(size_t)(n0 + row) * HH + k]);
            }
            xs[kk][row] = v;
        }
        // stage W tile (32k x 256 cols)
#pragma unroll
        for (int i = 0; i < 32; ++i) {
            int idx = t + i * 256;
            int kk = idx & 31, col = idx >> 5;
            int k = k0 + kk;
            float v = 0.f;
            if (k < F) v = W[(size_t)(c0 + col) * F + k];
            wsh[kk][col] = v;
        }
        __syncthreads();
#pragma unroll
        for (int kk = 0; kk < 32; ++kk) {
            float4 xv = *(const float4*)&xs[kk][rg * 4];
            float4 wv = *(const float4*)&wsh[kk][cg * 4];
            acc[0][0] += xv.x * wv.x; acc[0][1] += xv.x * wv.y; acc[0][2] += xv.x * wv.z; acc[0][3] += xv.x * wv.w;
            acc[1][0] += xv.y * wv.x; acc[1][1] += xv.y * wv.y; acc[1][2] += xv.y * wv.z; acc[1][3] += xv.y * wv.w;
            acc[2][0] += xv.z * wv.x; acc[2][1] += xv.z * wv.y; acc[2][2] += xv.z * wv.z; acc[2][3] += xv.z * wv.w;
            acc[3][0] += xv.w * wv.x; acc[3][1] += xv.w * wv.y; acc[3][2] += xv.w * wv.z; acc[3][3] += xv.w * wv.w;
        }
        __syncthreads();
    }

    float bc[4];
#pragma unroll
    for (int c = 0; c < 4; ++c) {
        int col = c0 + cg * 4 + c;
        bc[c] = bia[col] + bib[col];
    }
#pragma unroll
    for (int r = 0; r < 4; ++r) {
        int row = n0 + rg * 4 + r;
        ushort4 o;
        o.x = f2bf(acc[r][0] + bc[0]);
        o.y = f2bf(acc[r][1] + bc[1]);
        o.z = f2bf(acc[r][2] + bc[2]);
        o.w = f2bf(acc[r][3] + bc[3]);
        *(ushort4*)&g_xg[(size_t)row * GG + c0 + cg * 4] = o;
    }
}

// ---------- LSTM recurrence: one block per batch element ----------
// 512 threads: thread g computes gate g; W_hh row g kept in registers.
// LAYER 0: writes h (bf16) to g_h0.  LAYER 1: accumulates masked p-pool.
template <int LAYER>
__global__ __launch_bounds__(512) void lstm_kernel(
    const float* __restrict__ Whh,   // [512,128]
    const int* __restrict__ lens)
{
    const int b = blockIdx.x;
    const int g = threadIdx.x;

    __shared__ __align__(16) float h_lds[HH];
    __shared__ float gate_lds[GG];

    float w[HH];
#pragma unroll
    for (int k4 = 0; k4 < 32; ++k4) {
        float4 v = *(const float4*)&Whh[(size_t)g * HH + k4 * 4];
        w[k4 * 4 + 0] = v.x; w[k4 * 4 + 1] = v.y;
        w[k4 * 4 + 2] = v.z; w[k4 * 4 + 3] = v.w;
    }
    if (g < HH) h_lds[g] = 0.f;
    float c = 0.f;
    float pool = 0.f;
    const int len = lens[b];
    __syncthreads();

    float xcur = bf2f(g_xg[((size_t)0 * BB + b) * GG + g]);

    for (int t = 0; t < TT; ++t) {
        float xnext = 0.f;
        if (t + 1 < TT) xnext = bf2f(g_xg[((size_t)(t + 1) * BB + b) * GG + g]);

        float acc = xcur;
#pragma unroll
        for (int k4 = 0; k4 < 32; ++k4) {
            float4 hv = *(const float4*)&h_lds[k4 * 4];
            acc += w[k4 * 4 + 0] * hv.x;
            acc += w[k4 * 4 + 1] * hv.y;
            acc += w[k4 * 4 + 2] * hv.z;
            acc += w[k4 * 4 + 3] * hv.w;
        }
        // PyTorch gate order: i(0-127) f(128-255) g(256-383) o(384-511)
        float a = ((g >> 7) == 2) ? tanh_fast(acc) : sigm(acc);
        gate_lds[g] = a;
        __syncthreads();
        if (g < HH) {
            float i_ = gate_lds[g];
            float f_ = gate_lds[g + 128];
            float gg = gate_lds[g + 256];
            float o_ = gate_lds[g + 384];
            c = f_ * c + i_ * gg;
            float hv = o_ * tanh_fast(c);
            h_lds[g] = hv;
            if (LAYER == 0) {
                g_h0[((size_t)t * BB + b) * HH + g] = f2bf(hv);
            } else {
                if (t < len) {
                    float ah = fabsf(hv);
                    pool += ah * sqrtf(ah);   // |h|^1.5
                }
            }
        }
        __syncthreads();
        xcur = xnext;
    }

    if (LAYER == 1 && g < HH) {
        float s = powf(pool, 2.f / 3.f) * powf((float)len, -2.f / 3.f);
        g_pooled[b * HH + g] = s;
    }
}

// ---------- MLP + softmax ----------
__global__ __launch_bounds__(512) void mlp_kernel(
    const float* __restrict__ W1, const float* __restrict__ b1,
    const float* __restrict__ W2, const float* __restrict__ b2,
    float* __restrict__ out)
{
    const int b = blockIdx.x;
    const int t = threadIdx.x;
    __shared__ __align__(16) float pl[HH];
    __shared__ float x1[D1];
    __shared__ float lg[NOUT];

    if (t < HH) pl[t] = g_pooled[b * HH + t];
    __syncthreads();

    float acc = b1[t];
#pragma unroll
    for (int k4 = 0; k4 < 32; ++k4) {
        float4 wv = *(const float4*)&W1[(size_t)t * HH + k4 * 4];
        float4 pv = *(const float4*)&pl[k4 * 4];
        acc += wv.x * pv.x + wv.y * pv.y + wv.z * pv.z + wv.w * pv.w;
    }
    x1[t] = fmaxf(acc, 0.f);
    __syncthreads();

    if (t < NOUT) {
        float a = b2[t];
        for (int d = 0; d < D1; ++d) a += x1[d] * W2[(size_t)t * D1 + d];
        lg[t] = a;
    }
    __syncthreads();
    if (t < NOUT) {
        float m = lg[0];
#pragma unroll
        for (int j = 1; j < NOUT; ++j) m = fmaxf(m, lg[j]);
        float s = 0.f;
#pragma unroll
        for (int j = 0; j < NOUT; ++j) s += __expf(lg[j] - m);
        out[b * NOUT + t] = __expf(lg[t] - m) / s;
    }
}

// ---------- launch ----------
extern "C" void kernel_launch(void* const* d_in, const int* in_sizes, int n_in,
                              void* d_out, int out_size, void* d_ws, size_t ws_size,
                              hipStream_t stream)
{
    const float* x      = (const float*)d_in[0];
    const int*   lens   = (const int*)d_in[1];
    const float* W_ih0  = (const float*)d_in[2];
    const float* W_hh0  = (const float*)d_in[3];
    const float* b_ih0  = (const float*)d_in[4];
    const float* b_hh0  = (const float*)d_in[5];
    const float* W_ih1  = (const float*)d_in[6];
    const float* W_hh1  = (const float*)d_in[7];
    const float* b_ih1  = (const float*)d_in[8];
    const float* b_hh1  = (const float*)d_in[9];
    const float* W1     = (const float*)d_in[10];
    const float* b1     = (const float*)d_in[11];
    const float* W2     = (const float*)d_in[12];
    const float* b2     = (const float*)d_in[13];
    float* out = (float*)d_out;

    dim3 gg(TB / 16, 2);
    gemm_xg_kernel<0><<<gg, 256, 0, stream>>>(x, W_ih0, b_ih0, b_hh0);
    lstm_kernel<0><<<BB, 512, 0, stream>>>(W_hh0, lens);
    gemm_xg_kernel<1><<<gg, 256, 0, stream>>>(x, W_ih1, b_ih1, b_hh1);
    lstm_kernel<1><<<BB, 512, 0, stream>>>(W_hh1, lens);
    mlp_kernel<<<BB, 512, 0, stream>>>(W1, b1, W2, b2, out);
}

// Round 2
// 1362.670 us; speedup vs baseline: 6.5141x; 6.5141x over previous
//
#include <hip/hip_runtime.h>
#include <hip/hip_bf16.h>

// Problem constants
#define TT 512
#define BB 256
#define II 120
#define HH 128
#define GG 512   // 4*H
#define D1 512
#define NOUT 7
#define TB (TT*BB)  // 131072

// ---------- static device scratch ----------
__device__ unsigned short g_xg[TB * GG];   // [T*B, 512] bf16  (128 MB)
__device__ unsigned short g_h0[TB * HH];   // [T*B, 128] bf16  (32 MB)
__device__ float          g_pooled[BB * HH];

// ---------- helpers ----------
__device__ inline float bf2f(unsigned short u) {
    return __uint_as_float(((unsigned)u) << 16);
}
__device__ inline unsigned short f2bf(float f) {
    unsigned u = __float_as_uint(f);
    return (unsigned short)((u + 0x7fffu + ((u >> 16) & 1u)) >> 16);
}
__device__ inline float sigm(float x) {
    return 1.0f / (1.0f + __expf(-x));
}
__device__ inline float tanh_fast(float x) {
    x = fminf(fmaxf(x, -15.f), 15.f);
    float e = __expf(2.f * x);
    return (e - 1.f) / (e + 1.f);
}

// ---------- GEMM: xg[n,g] = sum_k A[n,k] * W[g,k] + bia[g] + bib[g] ----------
// 128x128 tile per 256-thread block; 8x8 micro-tile per thread; K chunked by 32.
// LAYER 0: A = input_seq (f32, F=120); LAYER 1: A = g_h0 (bf16, F=128)
#define KC 32
template <int LAYER>
__global__ __launch_bounds__(256) void gemm_xg_kernel(
    const float* __restrict__ A0,
    const float* __restrict__ W,      // [512, F]
    const float* __restrict__ bia,
    const float* __restrict__ bib)
{
    const int F  = (LAYER == 0) ? II : HH;
    const int m0 = blockIdx.x * 128;
    const int c0 = blockIdx.y * 128;
    const int t  = threadIdx.x;
    const int rg = t >> 4;    // 0..15 -> rows rg*8..rg*8+7
    const int cg = t & 15;    // 0..15 -> cols cg*8..cg*8+7

    __shared__ __align__(16) float As[KC][132];   // [kk][row]
    __shared__ __align__(16) float Ws[KC][132];   // [kk][col]

    float acc[8][8];
#pragma unroll
    for (int r = 0; r < 8; ++r)
#pragma unroll
        for (int c = 0; c < 8; ++c) acc[r][c] = 0.f;

    const int nchunk = (F + KC - 1) / KC;   // 4 for both layers
    for (int ch = 0; ch < nchunk; ++ch) {
        const int k0 = ch * KC;
        // stage A chunk: 128 rows x 32 k  (1024 float4 -> 4 per thread)
#pragma unroll
        for (int i = 0; i < 4; ++i) {
            int lin = t + i * 256;       // 0..1023
            int kv  = lin & 7;            // float4 slot (k = k0+kv*4)
            int row = lin >> 3;           // 0..127
            int k = k0 + kv * 4;
            float4 v = make_float4(0.f, 0.f, 0.f, 0.f);
            if (k < F) {                  // F%4==0, chunk-aligned -> full float4 safe
                if (LAYER == 0) {
                    v = *(const float4*)&A0[(size_t)(m0 + row) * II + k];
                } else {
                    ushort4 u = *(const ushort4*)&g_h0[(size_t)(m0 + row) * HH + k];
                    v = make_float4(bf2f(u.x), bf2f(u.y), bf2f(u.z), bf2f(u.w));
                }
            }
            As[kv * 4 + 0][row] = v.x;
            As[kv * 4 + 1][row] = v.y;
            As[kv * 4 + 2][row] = v.z;
            As[kv * 4 + 3][row] = v.w;
        }
        // stage W chunk: 128 cols x 32 k
#pragma unroll
        for (int i = 0; i < 4; ++i) {
            int lin = t + i * 256;
            int kv  = lin & 7;
            int col = lin >> 3;
            int k = k0 + kv * 4;
            float4 v = make_float4(0.f, 0.f, 0.f, 0.f);
            if (k < F) v = *(const float4*)&W[(size_t)(c0 + col) * F + k];
            Ws[kv * 4 + 0][col] = v.x;
            Ws[kv * 4 + 1][col] = v.y;
            Ws[kv * 4 + 2][col] = v.z;
            Ws[kv * 4 + 3][col] = v.w;
        }
        __syncthreads();
#pragma unroll 4
        for (int kk = 0; kk < KC; ++kk) {
            float4 a0 = *(const float4*)&As[kk][rg * 8];
            float4 a1 = *(const float4*)&As[kk][rg * 8 + 4];
            float4 w0 = *(const float4*)&Ws[kk][cg * 8];
            float4 w1 = *(const float4*)&Ws[kk][cg * 8 + 4];
            float av[8] = {a0.x, a0.y, a0.z, a0.w, a1.x, a1.y, a1.z, a1.w};
            float wv[8] = {w0.x, w0.y, w0.z, w0.w, w1.x, w1.y, w1.z, w1.w};
#pragma unroll
            for (int r = 0; r < 8; ++r)
#pragma unroll
                for (int c = 0; c < 8; ++c)
                    acc[r][c] += av[r] * wv[c];
        }
        __syncthreads();
    }

    float bcv[8];
#pragma unroll
    for (int c = 0; c < 8; ++c) {
        int col = c0 + cg * 8 + c;
        bcv[c] = bia[col] + bib[col];
    }
#pragma unroll
    for (int r = 0; r < 8; ++r) {
        int row = m0 + rg * 8 + r;
        ushort4 o0, o1;
        o0.x = f2bf(acc[r][0] + bcv[0]);
        o0.y = f2bf(acc[r][1] + bcv[1]);
        o0.z = f2bf(acc[r][2] + bcv[2]);
        o0.w = f2bf(acc[r][3] + bcv[3]);
        o1.x = f2bf(acc[r][4] + bcv[4]);
        o1.y = f2bf(acc[r][5] + bcv[5]);
        o1.z = f2bf(acc[r][6] + bcv[6]);
        o1.w = f2bf(acc[r][7] + bcv[7]);
        *(ushort4*)&g_xg[(size_t)row * GG + c0 + cg * 8]     = o0;
        *(ushort4*)&g_xg[(size_t)row * GG + c0 + cg * 8 + 4] = o1;
    }
}

// ---------- LSTM recurrence: one block per batch element ----------
template <int LAYER>
__global__ __launch_bounds__(512) void lstm_kernel(
    const float* __restrict__ Whh,   // [512,128]
    const int* __restrict__ lens)
{
    const int b = blockIdx.x;
    const int g = threadIdx.x;

    __shared__ __align__(16) float h_lds[HH];
    __shared__ float gate_lds[GG];

    float w[HH];
#pragma unroll
    for (int k4 = 0; k4 < 32; ++k4) {
        float4 v = *(const float4*)&Whh[(size_t)g * HH + k4 * 4];
        w[k4 * 4 + 0] = v.x; w[k4 * 4 + 1] = v.y;
        w[k4 * 4 + 2] = v.z; w[k4 * 4 + 3] = v.w;
    }
    if (g < HH) h_lds[g] = 0.f;
    float c = 0.f;
    float pool = 0.f;
    const int len = lens[b];
    __syncthreads();

    float xcur = bf2f(g_xg[((size_t)0 * BB + b) * GG + g]);

    for (int t = 0; t < TT; ++t) {
        float xnext = 0.f;
        if (t + 1 < TT) xnext = bf2f(g_xg[((size_t)(t + 1) * BB + b) * GG + g]);

        float acc = xcur;
#pragma unroll
        for (int k4 = 0; k4 < 32; ++k4) {
            float4 hv = *(const float4*)&h_lds[k4 * 4];
            acc += w[k4 * 4 + 0] * hv.x;
            acc += w[k4 * 4 + 1] * hv.y;
            acc += w[k4 * 4 + 2] * hv.z;
            acc += w[k4 * 4 + 3] * hv.w;
        }
        // PyTorch gate order: i(0-127) f(128-255) g(256-383) o(384-511)
        float a = ((g >> 7) == 2) ? tanh_fast(acc) : sigm(acc);
        gate_lds[g] = a;
        __syncthreads();
        if (g < HH) {
            float i_ = gate_lds[g];
            float f_ = gate_lds[g + 128];
            float gg = gate_lds[g + 256];
            float o_ = gate_lds[g + 384];
            c = f_ * c + i_ * gg;
            float hv = o_ * tanh_fast(c);
            h_lds[g] = hv;
            if (LAYER == 0) {
                g_h0[((size_t)t * BB + b) * HH + g] = f2bf(hv);
            } else {
                if (t < len) {
                    float ah = fabsf(hv);
                    pool += ah * sqrtf(ah);   // |h|^1.5
                }
            }
        }
        __syncthreads();
        xcur = xnext;
    }

    if (LAYER == 1 && g < HH) {
        float s = powf(pool, 2.f / 3.f) * powf((float)len, -2.f / 3.f);
        g_pooled[b * HH + g] = s;
    }
}

// ---------- MLP + softmax ----------
__global__ __launch_bounds__(512) void mlp_kernel(
    const float* __restrict__ W1, const float* __restrict__ b1,
    const float* __restrict__ W2, const float* __restrict__ b2,
    float* __restrict__ out)
{
    const int b = blockIdx.x;
    const int t = threadIdx.x;
    __shared__ __align__(16) float pl[HH];
    __shared__ float x1[D1];
    __shared__ float lg[NOUT];

    if (t < HH) pl[t] = g_pooled[b * HH + t];
    __syncthreads();

    float acc = b1[t];
#pragma unroll
    for (int k4 = 0; k4 < 32; ++k4) {
        float4 wv = *(const float4*)&W1[(size_t)t * HH + k4 * 4];
        float4 pv = *(const float4*)&pl[k4 * 4];
        acc += wv.x * pv.x + wv.y * pv.y + wv.z * pv.z + wv.w * pv.w;
    }
    x1[t] = fmaxf(acc, 0.f);
    __syncthreads();

    if (t < NOUT) {
        float a = b2[t];
        for (int d = 0; d < D1; ++d) a += x1[d] * W2[(size_t)t * D1 + d];
        lg[t] = a;
    }
    __syncthreads();
    if (t < NOUT) {
        float m = lg[0];
#pragma unroll
        for (int j = 1; j < NOUT; ++j) m = fmaxf(m, lg[j]);
        float s = 0.f;
#pragma unroll
        for (int j = 0; j < NOUT; ++j) s += __expf(lg[j] - m);
        out[b * NOUT + t] = __expf(lg[t] - m) / s;
    }
}

// ---------- launch ----------
extern "C" void kernel_launch(void* const* d_in, const int* in_sizes, int n_in,
                              void* d_out, int out_size, void* d_ws, size_t ws_size,
                              hipStream_t stream)
{
    const float* x      = (const float*)d_in[0];
    const int*   lens   = (const int*)d_in[1];
    const float* W_ih0  = (const float*)d_in[2];
    const float* W_hh0  = (const float*)d_in[3];
    const float* b_ih0  = (const float*)d_in[4];
    const float* b_hh0  = (const float*)d_in[5];
    const float* W_ih1  = (const float*)d_in[6];
    const float* W_hh1  = (const float*)d_in[7];
    const float* b_ih1  = (const float*)d_in[8];
    const float* b_hh1  = (const float*)d_in[9];
    const float* W1     = (const float*)d_in[10];
    const float* b1     = (const float*)d_in[11];
    const float* W2     = (const float*)d_in[12];
    const float* b2     = (const float*)d_in[13];
    float* out = (float*)d_out;

    dim3 gg(TB / 128, GG / 128);   // (1024, 4)
    gemm_xg_kernel<0><<<gg, 256, 0, stream>>>(x, W_ih0, b_ih0, b_hh0);
    lstm_kernel<0><<<BB, 512, 0, stream>>>(W_hh0, lens);
    gemm_xg_kernel<1><<<gg, 256, 0, stream>>>(x, W_ih1, b_ih1, b_hh1);
    lstm_kernel<1><<<BB, 512, 0, stream>>>(W_hh1, lens);
    mlp_kernel<<<BB, 512, 0, stream>>>(W1, b1, W2, b2, out);
}

// Round 3
// 1163.291 us; speedup vs baseline: 7.6305x; 1.1714x over previous
//
#include <hip/hip_runtime.h>
#include <hip/hip_bf16.h>

// Problem constants
#define TT 512
#define BB 256
#define II 120
#define HH 128
#define GG 512   // 4*H
#define D1 512
#define NOUT 7
#define TB (TT*BB)  // 131072

typedef _Float16 f16x2 __attribute__((ext_vector_type(2)));
typedef _Float16 f16x8 __attribute__((ext_vector_type(8)));

// ---------- static device scratch ----------
__device__ unsigned short g_xg[TB * GG];   // [T*B, 512] bf16  (128 MB)
__device__ unsigned short g_h0[TB * HH];   // [T*B, 128] bf16  (32 MB)
__device__ float          g_pooled[BB * HH];

// ---------- helpers ----------
__device__ inline float bf2f(unsigned short u) {
    return __uint_as_float(((unsigned)u) << 16);
}
__device__ inline unsigned short f2bf(float f) {
    unsigned u = __float_as_uint(f);
    return (unsigned short)((u + 0x7fffu + ((u >> 16) & 1u)) >> 16);
}
__device__ inline float sigm(float x) {
    return 1.0f / (1.0f + __expf(-x));
}
__device__ inline float tanh_fast(float x) {
    x = fminf(fmaxf(x, -15.f), 15.f);
    float e = __expf(2.f * x);
    return (e - 1.f) / (e + 1.f);
}

// ---------- GEMM: xg[n,g] = sum_k A[n,k] * W[g,k] + bia[g] + bib[g] ----------
// 128x128 tile per 256-thread block; 8x8 micro-tile per thread; K chunked by 32.
#define KC 32
template <int LAYER>
__global__ __launch_bounds__(256) void gemm_xg_kernel(
    const float* __restrict__ A0,
    const float* __restrict__ W,      // [512, F]
    const float* __restrict__ bia,
    const float* __restrict__ bib)
{
    const int F  = (LAYER == 0) ? II : HH;
    const int m0 = blockIdx.x * 128;
    const int c0 = blockIdx.y * 128;
    const int t  = threadIdx.x;
    const int rg = t >> 4;    // 0..15 -> rows rg*8..rg*8+7
    const int cg = t & 15;    // 0..15 -> cols cg*8..cg*8+7

    __shared__ __align__(16) float As[KC][132];   // [kk][row]
    __shared__ __align__(16) float Ws[KC][132];   // [kk][col]

    float acc[8][8];
#pragma unroll
    for (int r = 0; r < 8; ++r)
#pragma unroll
        for (int c = 0; c < 8; ++c) acc[r][c] = 0.f;

    const int nchunk = (F + KC - 1) / KC;   // 4 for both layers
    for (int ch = 0; ch < nchunk; ++ch) {
        const int k0 = ch * KC;
#pragma unroll
        for (int i = 0; i < 4; ++i) {
            int lin = t + i * 256;
            int kv  = lin & 7;
            int row = lin >> 3;
            int k = k0 + kv * 4;
            float4 v = make_float4(0.f, 0.f, 0.f, 0.f);
            if (k < F) {
                if (LAYER == 0) {
                    v = *(const float4*)&A0[(size_t)(m0 + row) * II + k];
                } else {
                    ushort4 u = *(const ushort4*)&g_h0[(size_t)(m0 + row) * HH + k];
                    v = make_float4(bf2f(u.x), bf2f(u.y), bf2f(u.z), bf2f(u.w));
                }
            }
            As[kv * 4 + 0][row] = v.x;
            As[kv * 4 + 1][row] = v.y;
            As[kv * 4 + 2][row] = v.z;
            As[kv * 4 + 3][row] = v.w;
        }
#pragma unroll
        for (int i = 0; i < 4; ++i) {
            int lin = t + i * 256;
            int kv  = lin & 7;
            int col = lin >> 3;
            int k = k0 + kv * 4;
            float4 v = make_float4(0.f, 0.f, 0.f, 0.f);
            if (k < F) v = *(const float4*)&W[(size_t)(c0 + col) * F + k];
            Ws[kv * 4 + 0][col] = v.x;
            Ws[kv * 4 + 1][col] = v.y;
            Ws[kv * 4 + 2][col] = v.z;
            Ws[kv * 4 + 3][col] = v.w;
        }
        __syncthreads();
#pragma unroll 4
        for (int kk = 0; kk < KC; ++kk) {
            float4 a0 = *(const float4*)&As[kk][rg * 8];
            float4 a1 = *(const float4*)&As[kk][rg * 8 + 4];
            float4 w0 = *(const float4*)&Ws[kk][cg * 8];
            float4 w1 = *(const float4*)&Ws[kk][cg * 8 + 4];
            float av[8] = {a0.x, a0.y, a0.z, a0.w, a1.x, a1.y, a1.z, a1.w};
            float wv[8] = {w0.x, w0.y, w0.z, w0.w, w1.x, w1.y, w1.z, w1.w};
#pragma unroll
            for (int r = 0; r < 8; ++r)
#pragma unroll
                for (int c = 0; c < 8; ++c)
                    acc[r][c] += av[r] * wv[c];
        }
        __syncthreads();
    }

    float bcv[8];
#pragma unroll
    for (int c = 0; c < 8; ++c) {
        int col = c0 + cg * 8 + c;
        bcv[c] = bia[col] + bib[col];
    }
#pragma unroll
    for (int r = 0; r < 8; ++r) {
        int row = m0 + rg * 8 + r;
        ushort4 o0, o1;
        o0.x = f2bf(acc[r][0] + bcv[0]);
        o0.y = f2bf(acc[r][1] + bcv[1]);
        o0.z = f2bf(acc[r][2] + bcv[2]);
        o0.w = f2bf(acc[r][3] + bcv[3]);
        o1.x = f2bf(acc[r][4] + bcv[4]);
        o1.y = f2bf(acc[r][5] + bcv[5]);
        o1.z = f2bf(acc[r][6] + bcv[6]);
        o1.w = f2bf(acc[r][7] + bcv[7]);
        *(ushort4*)&g_xg[(size_t)row * GG + c0 + cg * 8]     = o0;
        *(ushort4*)&g_xg[(size_t)row * GG + c0 + cg * 8 + 4] = o1;
    }
}

// ---------- LSTM recurrence: one block per batch element ----------
// Thread t -> (unit u = t>>2, gate part p = t&3; order i,f,g,o).
// Gate row in W_hh is r = p*128+u, so a unit's 4 gates sit in ADJACENT LANES:
// gate exchange = 3x __shfl_xor (no LDS, no barrier); cell update runs on all
// 512 threads with c replicated per quad. h double-buffered in LDS (f16) ->
// ONE barrier per step. Dot via v_dot2_f32_f16, 4 independent accumulators.
template <int LAYER>
__global__ __launch_bounds__(512) void lstm_kernel(
    const float* __restrict__ Whh,   // [512,128]
    const int* __restrict__ lens)
{
    const int b = blockIdx.x;
    const int t = threadIdx.x;
    const int u = t >> 2;       // unit 0..127
    const int p = t & 3;        // part: 0=i 1=f 2=g 3=o
    const int r = p * 128 + u;  // gate row

    __shared__ __align__(16) _Float16 h_lds[2][HH];

    // W_hh row r -> 64 packed half2
    f16x2 w2[64];
#pragma unroll
    for (int k4 = 0; k4 < 32; ++k4) {
        float4 v = *(const float4*)&Whh[(size_t)r * HH + k4 * 4];
        w2[k4 * 2 + 0] = f16x2{(_Float16)v.x, (_Float16)v.y};
        w2[k4 * 2 + 1] = f16x2{(_Float16)v.z, (_Float16)v.w};
    }
    if (t < HH) h_lds[0][t] = (_Float16)0.f;
    float c = 0.f, pool = 0.f;
    const int len = lens[b];
    __syncthreads();

    const unsigned short* xp = g_xg + (size_t)b * GG + r;
    float xcur = bf2f(xp[0]);
    int cur = 0;

    for (int step = 0; step < TT; ++step) {
        float xnext = 0.f;
        if (step + 1 < TT) xnext = bf2f(xp[(size_t)(step + 1) * (BB * GG)]);

        float a0 = xcur, a1 = 0.f, a2 = 0.f, a3 = 0.f;
#pragma unroll
        for (int k8 = 0; k8 < 16; ++k8) {
            f16x8 hv8 = *(const f16x8*)&h_lds[cur][k8 * 8];
            f16x2 h0 = {hv8[0], hv8[1]};
            f16x2 h1 = {hv8[2], hv8[3]};
            f16x2 h2 = {hv8[4], hv8[5]};
            f16x2 h3 = {hv8[6], hv8[7]};
#if __has_builtin(__builtin_amdgcn_fdot2)
            a0 = __builtin_amdgcn_fdot2(w2[k8 * 4 + 0], h0, a0, false);
            a1 = __builtin_amdgcn_fdot2(w2[k8 * 4 + 1], h1, a1, false);
            a2 = __builtin_amdgcn_fdot2(w2[k8 * 4 + 2], h2, a2, false);
            a3 = __builtin_amdgcn_fdot2(w2[k8 * 4 + 3], h3, a3, false);
#else
            a0 += (float)w2[k8*4+0][0]*(float)h0[0] + (float)w2[k8*4+0][1]*(float)h0[1];
            a1 += (float)w2[k8*4+1][0]*(float)h1[0] + (float)w2[k8*4+1][1]*(float)h1[1];
            a2 += (float)w2[k8*4+2][0]*(float)h2[0] + (float)w2[k8*4+2][1]*(float)h2[1];
            a3 += (float)w2[k8*4+3][0]*(float)h3[0] + (float)w2[k8*4+3][1]*(float)h3[1];
#endif
        }
        float acc = (a0 + a1) + (a2 + a3);

        // activation for own gate, then quad exchange via shuffles
        float act = (p == 2) ? tanh_fast(acc) : sigm(acc);
        float q1 = __shfl_xor(act, 1);
        float q2 = __shfl_xor(act, 2);
        float q3 = __shfl_xor(act, 3);
        // gate j sits at lane-distance p^j
        float i_ = (p == 0) ? act : (p == 1) ? q1 : (p == 2) ? q2 : q3;
        float f_ = (p == 1) ? act : (p == 0) ? q1 : (p == 3) ? q2 : q3;
        float g_ = (p == 2) ? act : (p == 3) ? q1 : (p == 0) ? q2 : q3;
        float o_ = (p == 3) ? act : (p == 2) ? q1 : (p == 1) ? q2 : q3;

        c = f_ * c + i_ * g_;          // replicated per quad
        float hv = o_ * tanh_fast(c);

        if (LAYER == 0) {
            if (p == 0) g_h0[((size_t)step * BB + b) * HH + u] = f2bf(hv);
        } else {
            if (step < len) {
                float ah = fabsf(hv);
                pool += ah * sqrtf(ah);   // |h|^1.5
            }
        }
        if (p == 0) h_lds[cur ^ 1][u] = (_Float16)hv;
        __syncthreads();
        cur ^= 1;
        xcur = xnext;
    }

    if (LAYER == 1 && p == 0) {
        float s = powf(pool, 2.f / 3.f) * powf((float)len, -2.f / 3.f);
        g_pooled[b * HH + u] = s;
    }
}

// ---------- MLP + softmax ----------
__global__ __launch_bounds__(512) void mlp_kernel(
    const float* __restrict__ W1, const float* __restrict__ b1,
    const float* __restrict__ W2, const float* __restrict__ b2,
    float* __restrict__ out)
{
    const int b = blockIdx.x;
    const int t = threadIdx.x;
    __shared__ __align__(16) float pl[HH];
    __shared__ float x1[D1];
    __shared__ float lg[NOUT];

    if (t < HH) pl[t] = g_pooled[b * HH + t];
    __syncthreads();

    float acc = b1[t];
#pragma unroll
    for (int k4 = 0; k4 < 32; ++k4) {
        float4 wv = *(const float4*)&W1[(size_t)t * HH + k4 * 4];
        float4 pv = *(const float4*)&pl[k4 * 4];
        acc += wv.x * pv.x + wv.y * pv.y + wv.z * pv.z + wv.w * pv.w;
    }
    x1[t] = fmaxf(acc, 0.f);
    __syncthreads();

    if (t < NOUT) {
        float a = b2[t];
        for (int d = 0; d < D1; ++d) a += x1[d] * W2[(size_t)t * D1 + d];
        lg[t] = a;
    }
    __syncthreads();
    if (t < NOUT) {
        float m = lg[0];
#pragma unroll
        for (int j = 1; j < NOUT; ++j) m = fmaxf(m, lg[j]);
        float s = 0.f;
#pragma unroll
        for (int j = 0; j < NOUT; ++j) s += __expf(lg[j] - m);
        out[b * NOUT + t] = __expf(lg[t] - m) / s;
    }
}

// ---------- launch ----------
extern "C" void kernel_launch(void* const* d_in, const int* in_sizes, int n_in,
                              void* d_out, int out_size, void* d_ws, size_t ws_size,
                              hipStream_t stream)
{
    const float* x      = (const float*)d_in[0];
    const int*   lens   = (const int*)d_in[1];
    const float* W_ih0  = (const float*)d_in[2];
    const float* W_hh0  = (const float*)d_in[3];
    const float* b_ih0  = (const float*)d_in[4];
    const float* b_hh0  = (const float*)d_in[5];
    const float* W_ih1  = (const float*)d_in[6];
    const float* W_hh1  = (const float*)d_in[7];
    const float* b_ih1  = (const float*)d_in[8];
    const float* b_hh1  = (const float*)d_in[9];
    const float* W1     = (const float*)d_in[10];
    const float* b1     = (const float*)d_in[11];
    const float* W2     = (const float*)d_in[12];
    const float* b2     = (const float*)d_in[13];
    float* out = (float*)d_out;

    dim3 gg(TB / 128, GG / 128);   // (1024, 4)
    gemm_xg_kernel<0><<<gg, 256, 0, stream>>>(x, W_ih0, b_ih0, b_hh0);
    lstm_kernel<0><<<BB, 512, 0, stream>>>(W_hh0, lens);
    gemm_xg_kernel<1><<<gg, 256, 0, stream>>>(x, W_ih1, b_ih1, b_hh1);
    lstm_kernel<1><<<BB, 512, 0, stream>>>(W_hh1, lens);
    mlp_kernel<<<BB, 512, 0, stream>>>(W1, b1, W2, b2, out);
}

// Round 4
// 1099.388 us; speedup vs baseline: 8.0740x; 1.0581x over previous
//
#include <hip/hip_runtime.h>
#include <hip/hip_bf16.h>

// Problem constants
#define TT 512
#define BB 256
#define II 120
#define HH 128
#define GG 512   // 4*H
#define D1 512
#define NOUT 7
#define TB (TT*BB)  // 131072

typedef _Float16 f16x2 __attribute__((ext_vector_type(2)));
typedef _Float16 f16x8 __attribute__((ext_vector_type(8)));

// ---------- static device scratch ----------
__device__ unsigned short g_xg[(size_t)TB * GG];   // [T*B, 512] bf16 (layer-0 input proj)
__device__ float          g_pooled[BB * HH];

// ---------- helpers ----------
__device__ inline float bf2f(unsigned short u) {
    return __uint_as_float(((unsigned)u) << 16);
}
__device__ inline unsigned short f2bf(float f) {
    unsigned u = __float_as_uint(f);
    return (unsigned short)((u + 0x7fffu + ((u >> 16) & 1u)) >> 16);
}
__device__ inline float sigm(float x) {
    return 1.0f / (1.0f + __expf(-x));
}
__device__ inline float tanh_fast(float x) {
    x = fminf(fmaxf(x, -15.f), 15.f);
    float e = __expf(2.f * x);
    return (e - 1.f) / (e + 1.f);
}
__device__ inline float fdot2(f16x2 a, f16x2 b, float c) {
#if __has_builtin(__builtin_amdgcn_fdot2)
    return __builtin_amdgcn_fdot2(a, b, c, false);
#else
    return c + (float)a[0] * (float)b[0] + (float)a[1] * (float)b[1];
#endif
}

// ---------- GEMM0: xg[n,g] = sum_k x[n,k] * W_ih0[g,k] + b_ih0[g] + b_hh0[g] ----------
// 128x128 tile per 256-thread block; 8x8 micro-tile per thread; K chunked by 32.
#define KC 32
__global__ __launch_bounds__(256) void gemm_xg_kernel(
    const float* __restrict__ A0,     // [TB, 120]
    const float* __restrict__ W,      // [512, 120]
    const float* __restrict__ bia,
    const float* __restrict__ bib)
{
    const int F  = II;
    const int m0 = blockIdx.x * 128;
    const int c0 = blockIdx.y * 128;
    const int t  = threadIdx.x;
    const int rg = t >> 4;
    const int cg = t & 15;

    __shared__ __align__(16) float As[KC][132];
    __shared__ __align__(16) float Ws[KC][132];

    float acc[8][8];
#pragma unroll
    for (int r = 0; r < 8; ++r)
#pragma unroll
        for (int c = 0; c < 8; ++c) acc[r][c] = 0.f;

    const int nchunk = (F + KC - 1) / KC;   // 4
    for (int ch = 0; ch < nchunk; ++ch) {
        const int k0 = ch * KC;
#pragma unroll
        for (int i = 0; i < 4; ++i) {
            int lin = t + i * 256;
            int kv  = lin & 7;
            int row = lin >> 3;
            int k = k0 + kv * 4;
            float4 v = make_float4(0.f, 0.f, 0.f, 0.f);
            if (k < F) v = *(const float4*)&A0[(size_t)(m0 + row) * II + k];
            As[kv * 4 + 0][row] = v.x;
            As[kv * 4 + 1][row] = v.y;
            As[kv * 4 + 2][row] = v.z;
            As[kv * 4 + 3][row] = v.w;
        }
#pragma unroll
        for (int i = 0; i < 4; ++i) {
            int lin = t + i * 256;
            int kv  = lin & 7;
            int col = lin >> 3;
            int k = k0 + kv * 4;
            float4 v = make_float4(0.f, 0.f, 0.f, 0.f);
            if (k < F) v = *(const float4*)&W[(size_t)(c0 + col) * F + k];
            Ws[kv * 4 + 0][col] = v.x;
            Ws[kv * 4 + 1][col] = v.y;
            Ws[kv * 4 + 2][col] = v.z;
            Ws[kv * 4 + 3][col] = v.w;
        }
        __syncthreads();
#pragma unroll 4
        for (int kk = 0; kk < KC; ++kk) {
            float4 a0 = *(const float4*)&As[kk][rg * 8];
            float4 a1 = *(const float4*)&As[kk][rg * 8 + 4];
            float4 w0 = *(const float4*)&Ws[kk][cg * 8];
            float4 w1 = *(const float4*)&Ws[kk][cg * 8 + 4];
            float av[8] = {a0.x, a0.y, a0.z, a0.w, a1.x, a1.y, a1.z, a1.w};
            float wv[8] = {w0.x, w0.y, w0.z, w0.w, w1.x, w1.y, w1.z, w1.w};
#pragma unroll
            for (int r = 0; r < 8; ++r)
#pragma unroll
                for (int c = 0; c < 8; ++c)
                    acc[r][c] += av[r] * wv[c];
        }
        __syncthreads();
    }

    float bcv[8];
#pragma unroll
    for (int c = 0; c < 8; ++c) {
        int col = c0 + cg * 8 + c;
        bcv[c] = bia[col] + bib[col];
    }
#pragma unroll
    for (int r = 0; r < 8; ++r) {
        int row = m0 + rg * 8 + r;
        ushort4 o0, o1;
        o0.x = f2bf(acc[r][0] + bcv[0]);
        o0.y = f2bf(acc[r][1] + bcv[1]);
        o0.z = f2bf(acc[r][2] + bcv[2]);
        o0.w = f2bf(acc[r][3] + bcv[3]);
        o1.x = f2bf(acc[r][4] + bcv[4]);
        o1.y = f2bf(acc[r][5] + bcv[5]);
        o1.z = f2bf(acc[r][6] + bcv[6]);
        o1.w = f2bf(acc[r][7] + bcv[7]);
        *(ushort4*)&g_xg[(size_t)row * GG + c0 + cg * 8]     = o0;
        *(ushort4*)&g_xg[(size_t)row * GG + c0 + cg * 8 + 4] = o1;
    }
}

// ---------- Fused 2-layer LSTM recurrence, L1 pipelined 1 step behind L0 ----------
// Thread t -> (unit u = t>>2, part p = t&3), gate row r = p*128+u.
// Per iteration k: phase A = layer-0 step k (xg0 from global, W_hh0 dot);
//                  phase B = layer-1 step k-1 (W_ih1·h0[k-1] + W_hh1·h1[k-2], both in-kernel).
// One barrier per iteration; h0/h1 double-buffered f16 in LDS.
// Weights: 3 rows x 64 f16x2 = 192 VGPRs held in registers.

#define PHASE_A(rd, wr, xin)                                              \
    {                                                                     \
        float aa0 = (xin), aa1 = 0.f, aa2 = 0.f, aa3 = 0.f;               \
        _Pragma("unroll")                                                 \
        for (int k8 = 0; k8 < 16; ++k8) {                                 \
            f16x8 hv = *(const f16x8*)&h0buf[rd][k8 * 8];                 \
            aa0 = fdot2(w0[k8 * 4 + 0], f16x2{hv[0], hv[1]}, aa0);        \
            aa1 = fdot2(w0[k8 * 4 + 1], f16x2{hv[2], hv[3]}, aa1);        \
            aa2 = fdot2(w0[k8 * 4 + 2], f16x2{hv[4], hv[5]}, aa2);        \
            aa3 = fdot2(w0[k8 * 4 + 3], f16x2{hv[6], hv[7]}, aa3);        \
        }                                                                 \
        float acc = (aa0 + aa1) + (aa2 + aa3);                            \
        float act = (p == 2) ? tanh_fast(acc) : sigm(acc);                \
        float i_ = __shfl(act, 0, 4);                                     \
        float f_ = __shfl(act, 1, 4);                                     \
        float g_ = __shfl(act, 2, 4);                                     \
        float o_ = __shfl(act, 3, 4);                                     \
        c0 = f_ * c0 + i_ * g_;                                           \
        float hvv = o_ * tanh_fast(c0);                                   \
        if (p == 0) h0buf[wr][u] = (_Float16)hvv;                         \
    }

#define PHASE_B(rd0, rdh, wrh, jstep)                                     \
    {                                                                     \
        float bb0 = bias1, bb1 = 0.f, bb2 = 0.f, bb3 = 0.f;               \
        _Pragma("unroll")                                                 \
        for (int k8 = 0; k8 < 16; ++k8) {                                 \
            f16x8 h0v = *(const f16x8*)&h0buf[rd0][k8 * 8];               \
            f16x8 h1v = *(const f16x8*)&h1buf[rdh][k8 * 8];               \
            bb0 = fdot2(wi[k8 * 4 + 0], f16x2{h0v[0], h0v[1]}, bb0);      \
            bb1 = fdot2(wi[k8 * 4 + 1], f16x2{h0v[2], h0v[3]}, bb1);      \
            bb2 = fdot2(wi[k8 * 4 + 2], f16x2{h0v[4], h0v[5]}, bb2);      \
            bb3 = fdot2(wi[k8 * 4 + 3], f16x2{h0v[6], h0v[7]}, bb3);      \
            bb0 = fdot2(wh[k8 * 4 + 0], f16x2{h1v[0], h1v[1]}, bb0);      \
            bb1 = fdot2(wh[k8 * 4 + 1], f16x2{h1v[2], h1v[3]}, bb1);      \
            bb2 = fdot2(wh[k8 * 4 + 2], f16x2{h1v[4], h1v[5]}, bb2);      \
            bb3 = fdot2(wh[k8 * 4 + 3], f16x2{h1v[6], h1v[7]}, bb3);      \
        }                                                                 \
        float acc = (bb0 + bb1) + (bb2 + bb3);                            \
        float act = (p == 2) ? tanh_fast(acc) : sigm(acc);                \
        float i_ = __shfl(act, 0, 4);                                     \
        float f_ = __shfl(act, 1, 4);                                     \
        float g_ = __shfl(act, 2, 4);                                     \
        float o_ = __shfl(act, 3, 4);                                     \
        c1 = f_ * c1 + i_ * g_;                                           \
        float hvv = o_ * tanh_fast(c1);                                   \
        if ((jstep) < len) {                                              \
            float ah = fabsf(hvv);                                        \
            pool += ah * sqrtf(ah);                                       \
        }                                                                 \
        if (p == 0) h1buf[wrh][u] = (_Float16)hvv;                        \
    }

__global__ __launch_bounds__(512) void lstm_fused_kernel(
    const float* __restrict__ Whh0,   // [512,128]
    const float* __restrict__ Wih1,   // [512,128]
    const float* __restrict__ Whh1,   // [512,128]
    const float* __restrict__ bi1,
    const float* __restrict__ bh1,
    const int* __restrict__ lens)
{
    const int b = blockIdx.x;
    const int t = threadIdx.x;
    const int u = t >> 2;
    const int p = t & 3;
    const int r = p * 128 + u;

    __shared__ __align__(16) _Float16 h0buf[2][HH];
    __shared__ __align__(16) _Float16 h1buf[2][HH];

    f16x2 w0[64], wi[64], wh[64];
#pragma unroll
    for (int k4 = 0; k4 < 32; ++k4) {
        float4 v0 = *(const float4*)&Whh0[(size_t)r * HH + k4 * 4];
        w0[k4 * 2 + 0] = f16x2{(_Float16)v0.x, (_Float16)v0.y};
        w0[k4 * 2 + 1] = f16x2{(_Float16)v0.z, (_Float16)v0.w};
        float4 vi = *(const float4*)&Wih1[(size_t)r * HH + k4 * 4];
        wi[k4 * 2 + 0] = f16x2{(_Float16)vi.x, (_Float16)vi.y};
        wi[k4 * 2 + 1] = f16x2{(_Float16)vi.z, (_Float16)vi.w};
        float4 vh = *(const float4*)&Whh1[(size_t)r * HH + k4 * 4];
        wh[k4 * 2 + 0] = f16x2{(_Float16)vh.x, (_Float16)vh.y};
        wh[k4 * 2 + 1] = f16x2{(_Float16)vh.z, (_Float16)vh.w};
    }
    const float bias1 = bi1[r] + bh1[r];
    if (t < HH) {
        h0buf[0][t] = (_Float16)0.f; h0buf[1][t] = (_Float16)0.f;
        h1buf[0][t] = (_Float16)0.f; h1buf[1][t] = (_Float16)0.f;
    }
    float c0 = 0.f, c1 = 0.f, pool = 0.f;
    const int len = lens[b];
    __syncthreads();

    const unsigned short* xp = g_xg + (size_t)b * GG + r;
    const size_t xstride = (size_t)BB * GG;

    float xcur = bf2f(xp[0]);

    // k = 0: layer-0 only
    PHASE_A(1, 0, xcur);
    __syncthreads();
    xcur = bf2f(xp[xstride]);

    for (int k = 1; k < TT; ++k) {
        float xnext = (k + 1 < TT) ? bf2f(xp[(size_t)(k + 1) * xstride]) : 0.f;
        const int wr = k & 1, rd = wr ^ 1;
        PHASE_A(rd, wr, xcur);
        PHASE_B(rd, wr, rd, k - 1);   // j=k-1: h0[j] in rd, h1[j-1] in wr, write h1[j] to rd
        __syncthreads();
        xcur = xnext;
    }
    // epilogue: layer-1 step TT-1
    PHASE_B((TT - 1) & 1, (TT - 2) & 1, (TT - 1) & 1, TT - 1);

    if (p == 0) {
        float s = powf(pool, 2.f / 3.f) * powf((float)len, -2.f / 3.f);
        g_pooled[b * HH + u] = s;
    }
}

// ---------- MLP + softmax ----------
__global__ __launch_bounds__(512) void mlp_kernel(
    const float* __restrict__ W1, const float* __restrict__ b1,
    const float* __restrict__ W2, const float* __restrict__ b2,
    float* __restrict__ out)
{
    const int b = blockIdx.x;
    const int t = threadIdx.x;
    __shared__ __align__(16) float pl[HH];
    __shared__ float x1[D1];
    __shared__ float lg[NOUT];

    if (t < HH) pl[t] = g_pooled[b * HH + t];
    __syncthreads();

    float acc = b1[t];
#pragma unroll
    for (int k4 = 0; k4 < 32; ++k4) {
        float4 wv = *(const float4*)&W1[(size_t)t * HH + k4 * 4];
        float4 pv = *(const float4*)&pl[k4 * 4];
        acc += wv.x * pv.x + wv.y * pv.y + wv.z * pv.z + wv.w * pv.w;
    }
    x1[t] = fmaxf(acc, 0.f);
    __syncthreads();

    if (t < NOUT) {
        float a = b2[t];
        for (int d = 0; d < D1; ++d) a += x1[d] * W2[(size_t)t * D1 + d];
        lg[t] = a;
    }
    __syncthreads();
    if (t < NOUT) {
        float m = lg[0];
#pragma unroll
        for (int j = 1; j < NOUT; ++j) m = fmaxf(m, lg[j]);
        float s = 0.f;
#pragma unroll
        for (int j = 0; j < NOUT; ++j) s += __expf(lg[j] - m);
        out[b * NOUT + t] = __expf(lg[t] - m) / s;
    }
}

// ---------- launch ----------
extern "C" void kernel_launch(void* const* d_in, const int* in_sizes, int n_in,
                              void* d_out, int out_size, void* d_ws, size_t ws_size,
                              hipStream_t stream)
{
    const float* x      = (const float*)d_in[0];
    const int*   lens   = (const int*)d_in[1];
    const float* W_ih0  = (const float*)d_in[2];
    const float* W_hh0  = (const float*)d_in[3];
    const float* b_ih0  = (const float*)d_in[4];
    const float* b_hh0  = (const float*)d_in[5];
    const float* W_ih1  = (const float*)d_in[6];
    const float* W_hh1  = (const float*)d_in[7];
    const float* b_ih1  = (const float*)d_in[8];
    const float* b_hh1  = (const float*)d_in[9];
    const float* W1     = (const float*)d_in[10];
    const float* b1     = (const float*)d_in[11];
    const float* W2     = (const float*)d_in[12];
    const float* b2     = (const float*)d_in[13];
    float* out = (float*)d_out;

    dim3 gg(TB / 128, GG / 128);   // (1024, 4)
    gemm_xg_kernel<<<gg, 256, 0, stream>>>(x, W_ih0, b_ih0, b_hh0);
    lstm_fused_kernel<<<BB, 512, 0, stream>>>(W_hh0, W_ih1, W_hh1, b_ih1, b_hh1, lens);
    mlp_kernel<<<BB, 512, 0, stream>>>(W1, b1, W2, b2, out);
}